// Round 6
// baseline (175.012 us; speedup 1.0000x reference)
//
#include <hip/hip_runtime.h>
#include <stdint.h>

// Problem constants (fixed by setup_inputs)
constexpr int B_SZ     = 128;
constexpr int IN_CAPS  = 1152;
constexpr int OUT_CAPS = 32;
constexpr int IN_D     = 8;
constexpr int OUT_D    = 16;
constexpr int ITERS    = 3;

constexpr int THREADS  = 1024;              // 16 waves
constexpr int NW       = THREADS / 64;      // 16
constexpr int G        = 2;                 // batches per block
constexpr int TILE_R   = 128;               // i-rows per LDS tile
constexpr int NTILE    = IN_CAPS / TILE_R;  // 9
constexpr int ROW_F    = 128;               // f32 per weight row (32 x 16B slots)

// async global->LDS, 16B per lane, dest = wave-uniform base + lane*16
typedef const uint32_t __attribute__((address_space(1)))* gptr_t;
typedef uint32_t       __attribute__((address_space(3)))* lptr_t;
__device__ __forceinline__ void async_copy16(const float* g, float* l) {
    __builtin_amdgcn_global_load_lds((gptr_t)g, (lptr_t)l, 16, 0, 0);
}

// One block per (j, batch-pair); thread = (bl = batch, mq = m-quarter,
// ir = i-row 0..127); uh[9][4] = 36 VGPRs.
//
// R5 lesson 1 (bank conflicts, 9.4M): bank group = slot&7; old perm put
// row-pairs (r,r+1) in the SAME 4 groups -> 2-way conflict per 16-lane phase.
// New perm(row) = (row&7) ^ ((row&1)<<2): rows r,r+1 get XOR-distance 5
// (bit2 flips) -> disjoint group halves; all 8 rows of a wave cover all 8
// groups per instruction. Applied on BOTH sides (global source pre-permuted
// for global_load_lds's linear LDS write; same XOR on ds_read side).
//
// R5 lesson 2 (occupancy 45%, VALUBusy 37%): 133 KB LDS -> 1 block/CU ->
// barriers/routing have nothing to overlap with. Single 64 KB buffer
// (68 KB total) -> 2 blocks/CU; the partner block hides stage-drain and
// routing serialization (inter-block pipelining instead of double-buffer).
__global__ __launch_bounds__(THREADS) void caps_route(
    const float* __restrict__ u,   // [B, IN_CAPS, IN_D]
    const float* __restrict__ w,   // [IN_CAPS, OUT_CAPS, IN_D, OUT_D]
    float* __restrict__ out)       // [B, OUT_CAPS, OUT_D]
{
    __shared__ __align__(16) float tile[TILE_R * ROW_F];     // 64 KB, single
    __shared__ float red_es[NW * 8];                         // esum partials
    __shared__ __align__(16) float red_m[NW * 8 * 4];        // s[4] partials

    // Bijective XCD swizzle (2048 % 8 == 0): j-major ids -> each XCD's L2
    // holds 4 j-columns (2.3 MB < 4 MB).
    const int nwg = gridDim.x;               // 2048
    const int bid = blockIdx.x;
    const int wid = (bid & 7) * (nwg >> 3) + (bid >> 3);
    const int j   = wid >> 6;                // 0..31
    const int b0  = (wid & 63) * G;          // 0..126 step 2

    const int tid  = threadIdx.x;
    const int lane = tid & 63;
    const int wv   = tid >> 6;               // wave 0..15
    const int bl   = tid & 1;                // batch within pair
    const int mq   = (tid >> 1) & 3;         // m-quarter (m = mq*4 + k)
    const int ir   = tid >> 3;               // i-row in tile, 0..127
    const int b    = b0 + bl;

    // read-side swizzle: chunk for (n = 2t+s, mq) lives at float offset
    // t*32 + ((s*4+mq) ^ perm(ir))*4 within the row.
    const int pmir = (ir & 7) ^ ((ir & 1) << 2);
    const int o0   = ((mq ^ pmir) << 2);          // s = 0 (even n)
    const int o1   = (((4 | mq) ^ pmir) << 2);    // s = 1 (odd n)

    float uh[NTILE][4];                      // 36 VGPRs, literal indexing
    float4 uA0, uA1;                         // u[b, i, :] for current tile

    // stage weight tile T into LDS (4 x 1KB wave-issues), source pre-permuted
    #define STAGE_TILE(T)                                                     \
    do {                                                                      \
        _Pragma("unroll")                                                     \
        for (int q = 0; q < 4; ++q) {                                         \
            const int Lb   = (wv * 4 + q) * 64;    /* chunk base, uniform */  \
            const int L    = Lb + lane;                                       \
            const int row  = L >> 5;                                          \
            const int slot = L & 31;                                          \
            const int c    = slot ^ ((row & 7) ^ ((row & 1) << 2));           \
            const float* gsrc = w +                                           \
                ((size_t)(((T) * TILE_R + row) * OUT_CAPS + j) * ROW_F + c * 4); \
            async_copy16(gsrc, &tile[Lb * 4]);                                \
        }                                                                     \
    } while (0)

    #define ULOAD(T)                                                          \
    do {                                                                      \
        const float* up = u + ((size_t)b * IN_CAPS + (T) * TILE_R + ir) * IN_D; \
        uA0 = *reinterpret_cast<const float4*>(up);                           \
        uA1 = *reinterpret_cast<const float4*>(up + 4);                       \
    } while (0)

    // compute uh[T][0..3] for my (i-row, b, m-quarter)
    #define COMP_TILE(T)                                                      \
    do {                                                                      \
        const float* trow = &tile[ir * ROW_F];                                \
        const float uc[8] = {uA0.x, uA0.y, uA0.z, uA0.w,                      \
                             uA1.x, uA1.y, uA1.z, uA1.w};                     \
        float4 acc = make_float4(0.f, 0.f, 0.f, 0.f);                         \
        _Pragma("unroll")                                                     \
        for (int t = 0; t < 4; ++t) {                                         \
            const float4 wa = *reinterpret_cast<const float4*>(trow + t * 32 + o0); \
            const float4 wb = *reinterpret_cast<const float4*>(trow + t * 32 + o1); \
            acc.x = fmaf(uc[2*t], wa.x, acc.x);                               \
            acc.y = fmaf(uc[2*t], wa.y, acc.y);                               \
            acc.z = fmaf(uc[2*t], wa.z, acc.z);                               \
            acc.w = fmaf(uc[2*t], wa.w, acc.w);                               \
            acc.x = fmaf(uc[2*t+1], wb.x, acc.x);                             \
            acc.y = fmaf(uc[2*t+1], wb.y, acc.y);                             \
            acc.z = fmaf(uc[2*t+1], wb.z, acc.z);                             \
            acc.w = fmaf(uc[2*t+1], wb.w, acc.w);                             \
        }                                                                     \
        uh[(T)][0] = acc.x; uh[(T)][1] = acc.y;                               \
        uh[(T)][2] = acc.z; uh[(T)][3] = acc.w;                               \
    } while (0)

    // step T>=1: barrier (reads of T-1 done) | stage T | barrier (drain,
    // compiler emits s_waitcnt vmcnt(0) before s_barrier) | compute T.
    // The partner block on the CU fills the drain gaps.
    #define STEP(T)                                                           \
    do {                                                                      \
        __syncthreads();                                                      \
        STAGE_TILE(T);                                                        \
        ULOAD(T);                                                             \
        __syncthreads();                                                      \
        COMP_TILE(T);                                                         \
    } while (0)

    // ---- prologue + 9 tile steps ----
    STAGE_TILE(0);
    ULOAD(0);
    __syncthreads();
    COMP_TILE(0);
    STEP(1); STEP(2); STEP(3); STEP(4);
    STEP(5); STEP(6); STEP(7); STEP(8);
    #undef STEP
    #undef COMP_TILE
    #undef ULOAD
    #undef STAGE_TILE

    // ================= routing iterations =================
    // exp-domain logits: e[r] = exp(b[r]); update e *= exp(a). Saves the
    // blog[] array (9 VGPRs). iter 0: e = exp(0) = 1 exactly.
    float e[NTILE];
    #pragma unroll
    for (int r = 0; r < NTILE; ++r) e[r] = 1.0f;
    float vv[4];
    const int grp = lane & 7;                // (mq<<1)|bl

    for (int it = 0; it < ITERS; ++it) {
        float esum = 0.0f;
        #pragma unroll
        for (int r = 0; r < NTILE; ++r) esum += e[r];
        esum += __shfl_xor(esum, 8);
        esum += __shfl_xor(esum, 16);
        esum += __shfl_xor(esum, 32);

        // s-partials for my m-quarter
        float sp0 = 0.f, sp1 = 0.f, sp2 = 0.f, sp3 = 0.f;
        #pragma unroll
        for (int r = 0; r < NTILE; ++r) {
            sp0 = fmaf(e[r], uh[r][0], sp0);
            sp1 = fmaf(e[r], uh[r][1], sp1);
            sp2 = fmaf(e[r], uh[r][2], sp2);
            sp3 = fmaf(e[r], uh[r][3], sp3);
        }
        sp0 += __shfl_xor(sp0, 8);  sp1 += __shfl_xor(sp1, 8);
        sp2 += __shfl_xor(sp2, 8);  sp3 += __shfl_xor(sp3, 8);
        sp0 += __shfl_xor(sp0, 16); sp1 += __shfl_xor(sp1, 16);
        sp2 += __shfl_xor(sp2, 16); sp3 += __shfl_xor(sp3, 16);
        sp0 += __shfl_xor(sp0, 32); sp1 += __shfl_xor(sp1, 32);
        sp2 += __shfl_xor(sp2, 32); sp3 += __shfl_xor(sp3, 32);

        if (lane < 8) {   // lane == (mq<<1)|bl of ir-group 0
            red_es[wv * 8 + lane] = esum;
            *reinterpret_cast<float4*>(&red_m[(wv * 8 + lane) * 4]) =
                make_float4(sp0, sp1, sp2, sp3);
        }
        __syncthreads();
        float gsum = 0.0f;
        float sa0 = 0.f, sa1 = 0.f, sa2 = 0.f, sa3 = 0.f;
        #pragma unroll
        for (int q = 0; q < NW; ++q) {
            gsum += red_es[q * 8 + grp];
            const float4 rm =
                *reinterpret_cast<const float4*>(&red_m[(q * 8 + grp) * 4]);
            sa0 += rm.x; sa1 += rm.y; sa2 += rm.z; sa3 += rm.w;
        }
        __syncthreads();   // reads done before next iteration's writes

        const float cinv = 1.0f / gsum;
        vv[0] = sa0 * cinv; vv[1] = sa1 * cinv;
        vv[2] = sa2 * cinv; vv[3] = sa3 * cinv;
        float s2 = fmaf(vv[0], vv[0], fmaf(vv[1], vv[1],
                   fmaf(vv[2], vv[2], vv[3] * vv[3])));
        s2 += __shfl_xor(s2, 2);   // combine the 4 m-quarters (same bl)
        s2 += __shfl_xor(s2, 4);
        const float scale = (s2 / (1.0f + s2)) * rsqrtf(s2 + 1e-8f);
        vv[0] *= scale; vv[1] *= scale; vv[2] *= scale; vv[3] *= scale;

        // logit update: a = sum_m v[m]*uh[i][m]; combine mq via masks 2,4
        if (it < ITERS - 1) {
            #pragma unroll
            for (int r = 0; r < NTILE; ++r) {
                float a = fmaf(vv[0], uh[r][0], fmaf(vv[1], uh[r][1],
                          fmaf(vv[2], uh[r][2], vv[3] * uh[r][3])));
                a += __shfl_xor(a, 2);
                a += __shfl_xor(a, 4);
                e[r] *= __expf(a);
            }
        }
    }

    // ---- write v[b0+bl, j, mq*4 .. mq*4+3] ----
    if (tid < 8) {
        float4* op = reinterpret_cast<float4*>(
            out + ((size_t)(b0 + bl) * OUT_CAPS + j) * OUT_D + mq * 4);
        *op = make_float4(vv[0], vv[1], vv[2], vv[3]);
    }
}

extern "C" void kernel_launch(void* const* d_in, const int* in_sizes, int n_in,
                              void* d_out, int out_size, void* d_ws, size_t ws_size,
                              hipStream_t stream) {
    const float* u = (const float*)d_in[0];   // [128, 1152, 8]
    const float* w = (const float*)d_in[1];   // [1152, 32, 8, 16]
    float* out     = (float*)d_out;           // [128, 32, 16]
    (void)in_sizes; (void)n_in; (void)out_size; (void)d_ws; (void)ws_size;

    dim3 grid(OUT_CAPS * (B_SZ / G));   // 32 j x 64 batch-pairs = 2048 blocks
    dim3 block(THREADS);                // 1024 threads = 16 waves
    hipLaunchKernelGGL(caps_route, grid, block, 0, stream, u, w, out);
}